// Round 10
// baseline (754.885 us; speedup 1.0000x reference)
//
#include <hip/hip_runtime.h>

#define BSZ   4
#define WSEQ  768
#define LSEQ  8192
#define NFFT  8192   // packed complex FFT length (real length 16384)
#define MH    4096
#define EMB   33
#define ORDER 64
#define NT    512    // threads per FFT block

// workspace layout (float units)
#define KFROW   16392          // per-w row: k reals (8192) then 8193 complex in-place
#define WS_TWN  0              // 8192 complex  e^{-2pi t/8192}  (full circle)
#define WS_TW2N 16384          // 8192 complex  e^{-2pi k/16384}
#define WS_H    32768          // h_T: [64][8192] (o-major)
#define WS_KF   557056         // 768 rows x KFROW floats (~50.1 MiB total)

__device__ __forceinline__ int swz(int a){ return a ^ (((a >> 5) & 7) << 2); }

// ---------------- twiddle tables (built in fp64 once per launch) ----------------
__global__ void tables_kernel(float* __restrict__ ws){
  int t = blockIdx.x * 256 + threadIdx.x;      // 0..8191
  const double TWO_PI = 6.283185307179586476925286766559;
  double a1 = -TWO_PI * (double)t / 8192.0;
  double a2 = -TWO_PI * (double)t / 16384.0;
  ws[WS_TWN  + 2*t]   = (float)cos(a1);
  ws[WS_TWN  + 2*t+1] = (float)sin(a1);
  ws[WS_TW2N + 2*t]   = (float)cos(a2);
  ws[WS_TW2N + 2*t+1] = (float)sin(a2);
}

// ---------------- implicit filter MLP: z[8192,33] -> h_T[64][8192] ----------------
__global__ void mlp_kernel(const float* __restrict__ z, const float* __restrict__ freq,
                           const float* __restrict__ w0, const float* __restrict__ b0,
                           const float* __restrict__ w1, const float* __restrict__ b1,
                           const float* __restrict__ w2, const float* __restrict__ b2,
                           float* __restrict__ ws){
  int l = blockIdx.x * 256 + threadIdx.x;
  if (l >= LSEQ) return;
  float zv[EMB];
  #pragma unroll
  for (int e = 0; e < EMB; ++e) zv[e] = z[l*EMB + e];
  float h1[ORDER];
  #pragma unroll 2
  for (int o = 0; o < ORDER; ++o){
    float a = b0[o];
    #pragma unroll
    for (int e = 0; e < EMB; ++e) a += zv[e] * w0[e*ORDER + o];
    h1[o] = sinf(freq[o] * a);
  }
  float h2[ORDER];
  #pragma unroll 2
  for (int o = 0; o < ORDER; ++o){
    float a = b1[o];
    #pragma unroll
    for (int p = 0; p < ORDER; ++p) a += h1[p] * w1[p*ORDER + o];
    h2[o] = sinf(freq[o] * a);
  }
  #pragma unroll 2
  for (int o = 0; o < ORDER; ++o){
    float a = b2[o];
    #pragma unroll
    for (int p = 0; p < ORDER; ++p) a += h2[p] * w2[p*ORDER + o];
    ws[WS_H + o*LSEQ + l] = sinf(freq[o] * a);   // transposed, coalesced per o
  }
}

// ---------------- kgemm: k[w,l] = (h_T[:,l]·wf[:,w]) * exp(-t_l*|delta_w|) ----------------
__global__ void __launch_bounds__(256, 2)
kgemm_kernel(const float* __restrict__ wf, const float* __restrict__ deltas,
             float* __restrict__ ws){
  __shared__ float As[64][128];   // [o][l] 32 KB
  __shared__ float Bs[64][128];   // [o][w] 32 KB
  const int tid = threadIdx.x;
  const int lb = (blockIdx.x & 63) << 7;
  const int wb = (blockIdx.x >> 6) << 7;
  #pragma unroll
  for (int q = 0; q < 8; ++q){
    int idx = q*256 + tid;
    int o = idx >> 5;
    int c = (idx & 31) << 2;
    *(float4*)&As[o][c] = *(const float4*)&ws[WS_H + o*LSEQ + lb + c];
    *(float4*)&Bs[o][c] = *(const float4*)&wf[o*WSEQ + wb + c];
  }
  __syncthreads();
  const int tx = tid & 15;
  const int ty = tid >> 4;
  float acc[8][8];
  #pragma unroll
  for (int i = 0; i < 8; ++i)
    #pragma unroll
    for (int j = 0; j < 8; ++j) acc[i][j] = 0.f;
  #pragma unroll 4
  for (int ko = 0; ko < 64; ++ko){
    float a[8], b[8];
    #pragma unroll
    for (int i = 0; i < 8; ++i) a[i] = As[ko][ty*8 + i];
    #pragma unroll
    for (int j = 0; j < 8; ++j) b[j] = Bs[ko][tx + j*16];
    #pragma unroll
    for (int i = 0; i < 8; ++i)
      #pragma unroll
      for (int j = 0; j < 8; ++j) acc[i][j] += a[i]*b[j];
  }
  const float ool = 1.0f / 8191.0f;
  #pragma unroll
  for (int j = 0; j < 8; ++j){
    int w = wb + tx + j*16;
    float ad = fabsf(deltas[w]);
    float e[8];
    #pragma unroll
    for (int i = 0; i < 8; ++i){
      float tl = (float)(lb + ty*8 + i) * ool;
      e[i] = acc[i][j] * __expf(-tl * ad);
    }
    float* dst = ws + WS_KF + (size_t)w*KFROW + lb + ty*8;
    *(float4*)dst       = make_float4(e[0], e[1], e[2], e[3]);
    *(float4*)(dst + 4) = make_float4(e[4], e[5], e[6], e[7]);
  }
}

// ---------------- Stockham radix-4 pass (in-place, register-staged) ----------------
// Twiddles read directly from full-circle table: w1=tw[i1], w2=tw[2*i1], w3=tw[3*i1].
template<int SGN>
__device__ __forceinline__ void pass_r4(float2* sC,
        const float2* __restrict__ twN, int tid, int l2){
  const int ns = 1 << l2;
  const int sh = 11 - l2;
  float2 o[4][4];
  int bas[4];
  #pragma unroll
  for (int i = 0; i < 4; ++i){
    int j = tid + (i << 9);
    int u = j & (ns - 1);
    int i1 = u << sh;
    float2 t1 = twN[i1];
    float2 t2 = twN[2*i1];
    float2 t3 = twN[3*i1];
    float w1r = t1.x, w1i = (SGN > 0) ? t1.y : -t1.y;
    float w2r = t2.x, w2i = (SGN > 0) ? t2.y : -t2.y;
    float w3r = t3.x, w3i = (SGN > 0) ? t3.y : -t3.y;
    float2 v0 = sC[swz(j)];
    float2 a1 = sC[swz(j+2048)];
    float2 a2 = sC[swz(j+4096)];
    float2 a3 = sC[swz(j+6144)];
    float v1r = a1.x*w1r - a1.y*w1i, v1i = a1.x*w1i + a1.y*w1r;
    float v2r = a2.x*w2r - a2.y*w2i, v2i = a2.x*w2i + a2.y*w2r;
    float v3r = a3.x*w3r - a3.y*w3i, v3i = a3.x*w3i + a3.y*w3r;
    float t0r = v0.x+v2r, t0i = v0.y+v2i;
    float t1r_ = v0.x-v2r, t1i_ = v0.y-v2i;
    float t2r = v1r+v3r, t2i = v1i+v3i;
    float t3r = v1r-v3r, t3i = v1i-v3i;
    o[i][0] = make_float2(t0r+t2r, t0i+t2i);
    o[i][2] = make_float2(t0r-t2r, t0i-t2i);
    if (SGN > 0){
      o[i][1] = make_float2(t1r_ + t3i, t1i_ - t3r);
      o[i][3] = make_float2(t1r_ - t3i, t1i_ + t3r);
    } else {
      o[i][1] = make_float2(t1r_ - t3i, t1i_ + t3r);
      o[i][3] = make_float2(t1r_ + t3i, t1i_ - t3r);
    }
    bas[i] = ((j >> l2) << (l2 + 2)) + u;
  }
  __syncthreads();
  #pragma unroll
  for (int i = 0; i < 4; ++i){
    #pragma unroll
    for (int r = 0; r < 4; ++r){
      sC[swz(bas[i] + (r << l2))] = o[i][r];
    }
  }
  __syncthreads();
}

template<int SGN>
__device__ __forceinline__ void fft_passes(float2* sC,
        const float2* __restrict__ twN, int tid){
  #pragma unroll 1
  for (int p = 0; p < 6; ++p)
    pass_r4<SGN>(sC, twN, tid, 1 + 2*p);
}

// full radix-2 first pass for the inverse (Ns=1, no twiddle)
__device__ __forceinline__ void pass_r2_first(float2* sC, int tid){
  float4 v[8];
  #pragma unroll
  for (int i = 0; i < 8; ++i){
    int j = tid + (i << 9);
    float2 a = sC[swz(j)];
    float2 b = sC[swz(j+4096)];
    v[i] = make_float4(a.x+b.x, a.y+b.y, a.x-b.x, a.y-b.y);
  }
  __syncthreads();
  #pragma unroll
  for (int i = 0; i < 8; ++i){
    int j = tid + (i << 9);
    ((float4*)sC)[swz(2*j) >> 1] = v[i];   // covers swz(2j), swz(2j)+1 == swz(2j+1)
  }
  __syncthreads();
}

// unpack packed-complex FFT C -> real spectrum pair U[t], U[N-t]
__device__ __forceinline__ void unpack_item(int t, const float2* sC,
        const float2* __restrict__ tw2N,
        float& Ukr, float& Uki, float& Unr, float& Uni){
  int tn = (NFFT - t) & (NFFT - 1);
  float2 a = sC[swz(t)];
  float2 b = sC[swz(tn)];
  float Er = 0.5f*(a.x+b.x), Ei = 0.5f*(a.y-b.y);
  float Pr = 0.5f*(a.x-b.x), Pi = 0.5f*(a.y+b.y);
  float Or = Pi, Oi = -Pr;                       // O = -i*P
  float2 tw = tw2N[t];                           // e^{-i pi t / N}
  float Qr = Or*tw.x - Oi*tw.y, Qi = Or*tw.y + Oi*tw.x;
  Ukr = Er + Qr; Uki = Ei + Qi;                  // U[t]   = E + Q
  Unr = Er - Qr; Uni = Qi - Ei;                  // U[N-t] = conj(E - Q)
}

// ---------------- per-w filter spectrum: K = rfft(k,16384)/16384 ----------------
__global__ void __launch_bounds__(NT, 2)
fftk_kernel(float* __restrict__ ws){
  __shared__ float2 sC[NFFT];
  const int tid = threadIdx.x;
  const int w = blockIdx.x;
  float* kfr = ws + WS_KF + (size_t)w * KFROW;
  const float2* twN  = (const float2*)(ws + WS_TWN);
  const float2* tw2N = (const float2*)(ws + WS_TW2N);
  #pragma unroll
  for (int q = 0; q < 8; ++q){                   // pack + trivial first radix-2 (zero pad)
    int j = tid + (q << 9);
    float2 v = ((const float2*)kfr)[j];
    ((float4*)sC)[swz(2*j) >> 1] = make_float4(v.x, v.y, v.x, v.y);
  }
  __syncthreads();
  fft_passes<1>(sC, twN, tid);
  const float sc = 1.0f / 16384.0f;
  #pragma unroll
  for (int i = 0; i < 8; ++i){
    int t = tid + (i << 9);
    float Ukr, Uki, Unr, Uni;
    unpack_item(t, sC, tw2N, Ukr, Uki, Unr, Uni);
    ((float2*)kfr)[t]        = make_float2(Ukr*sc, Uki*sc);
    ((float2*)kfr)[NFFT - t] = make_float2(Unr*sc, Uni*sc);
  }
  if (tid == 0){
    float Ukr, Uki, Unr, Uni;
    unpack_item(MH, sC, tw2N, Ukr, Uki, Unr, Uni);
    ((float2*)kfr)[MH] = make_float2(Ukr*sc, Uki*sc);
  }
}

// fused unpack -> multiply by K -> repack for inverse
__device__ __forceinline__ void pair_item(int t, const float2* sC,
        const float* __restrict__ kfr, const float2* __restrict__ tw2N,
        float& Dtr, float& Dti, float& Dnr, float& Dni){
  float Ukr, Uki, Unr, Uni;
  unpack_item(t, sC, tw2N, Ukr, Uki, Unr, Uni);
  float2 tw = tw2N[t];
  float2 Kk = ((const float2*)kfr)[t];
  float2 Kn = ((const float2*)kfr)[NFFT - t];
  float Ykr = Ukr*Kk.x - Uki*Kk.y, Yki = Ukr*Kk.y + Uki*Kk.x;
  float Ynr = Unr*Kn.x - Uni*Kn.y, Yni = Unr*Kn.y + Uni*Kn.x;
  float Ar = Ykr + Ynr, Ai = Yki - Yni;          // A = Yk + conj(Yn)
  float Br = Ykr - Ynr, Bi = Yki + Yni;          // B = Yk - conj(Yn)
  float Rr = Br*tw.x + Bi*tw.y;                  // R = conj(tw) * B
  float Ri = Bi*tw.x - Br*tw.y;
  Dtr = Ar - Ri; Dti = Ai + Rr;                  // D[t]   = A + iR
  Dnr = Ar + Ri; Dni = Rr - Ai;                  // D[N-t] = conj(A - iR)
}

// ---------------- main: per (b,w) row FFT convolution ----------------
__global__ void __launch_bounds__(NT, 2)
conv_kernel(const float* __restrict__ x, const float* __restrict__ ws,
            const float* __restrict__ Dw, float* __restrict__ out){
  __shared__ float2 sC[NFFT];
  const int tid = threadIdx.x;
  // XCD-aware swizzle: the 4 blocks sharing one K row co-reside on one XCD.
  const int blk = (blockIdx.x & 7) * 384 + (blockIdx.x >> 3);
  const int b = blk & 3, w = blk >> 2;
  const float2* twN  = (const float2*)(ws + WS_TWN);
  const float2* tw2N = (const float2*)(ws + WS_TW2N);
  const float* kfr = ws + WS_KF + (size_t)w * KFROW;
  const size_t rowoff = ((size_t)(b*WSEQ + w)) * LSEQ;
  const float2* xrow = (const float2*)(x + rowoff);
  float2 xr[8];
  #pragma unroll
  for (int q = 0; q < 8; ++q){                   // load row, pack, trivial first pass
    int j = tid + (q << 9);
    float2 v = xrow[j];
    xr[q] = v;
    ((float4*)sC)[swz(2*j) >> 1] = make_float4(v.x, v.y, v.x, v.y);
  }
  __syncthreads();
  fft_passes<1>(sC, twN, tid);                   // forward
  // pair phase (register staged: read all C, then write all D)
  float2 Dt[8], Dn[8];
  float etr = 0.f, eti = 0.f;
  #pragma unroll
  for (int i = 0; i < 8; ++i){
    int t = tid + (i << 9);
    float a, bq, c, d;
    pair_item(t, sC, kfr, tw2N, a, bq, c, d);
    Dt[i] = make_float2(a, bq); Dn[i] = make_float2(c, d);
  }
  if (tid == 0){
    float a, bq, c, d;
    pair_item(MH, sC, kfr, tw2N, a, bq, c, d);
    etr = a; eti = bq;
  }
  __syncthreads();
  #pragma unroll
  for (int i = 0; i < 8; ++i){
    int t = tid + (i << 9);
    int tn = (NFFT - t) & (NFFT - 1);
    sC[swz(t)]  = Dt[i];
    sC[swz(tn)] = Dn[i];
  }
  if (tid == 0){ sC[swz(MH)] = make_float2(etr, eti); }
  __syncthreads();
  // inverse: radix-2 full pass + 6 conjugate radix-4 passes
  pass_r2_first(sC, tid);
  fft_passes<-1>(sC, twN, tid);
  // epilogue: y[2j],y[2j+1] = Re/Im d[j]; add residual x*D[w]
  const float dsc = Dw[w];
  float2* orow = (float2*)(out + rowoff);
  #pragma unroll
  for (int q = 0; q < 8; ++q){
    int j = tid + (q << 9);
    float2 dv = sC[swz(j)];
    float2 o;
    o.x = dv.x + xr[q].x * dsc;
    o.y = dv.y + xr[q].y * dsc;
    orow[j] = o;
  }
}

extern "C" void kernel_launch(void* const* d_in, const int* in_sizes, int n_in,
                              void* d_out, int out_size, void* d_ws, size_t ws_size,
                              hipStream_t stream){
  const float* x      = (const float*)d_in[0];
  const float* z      = (const float*)d_in[1];
  const float* freq   = (const float*)d_in[2];
  const float* w0     = (const float*)d_in[3];
  const float* b0     = (const float*)d_in[4];
  const float* w1     = (const float*)d_in[5];
  const float* b1     = (const float*)d_in[6];
  const float* w2     = (const float*)d_in[7];
  const float* b2     = (const float*)d_in[8];
  const float* wf     = (const float*)d_in[9];
  const float* deltas = (const float*)d_in[10];
  const float* Dw     = (const float*)d_in[11];
  float* ws  = (float*)d_ws;
  float* out = (float*)d_out;

  tables_kernel<<<dim3(32),  dim3(256), 0, stream>>>(ws);
  mlp_kernel   <<<dim3(32),  dim3(256), 0, stream>>>(z, freq, w0, b0, w1, b1, w2, b2, ws);
  kgemm_kernel <<<dim3(384), dim3(256), 0, stream>>>(wf, deltas, ws);
  fftk_kernel  <<<dim3(WSEQ), dim3(NT), 0, stream>>>(ws);
  conv_kernel  <<<dim3(BSZ*WSEQ), dim3(NT), 0, stream>>>(x, ws, Dw, out);
}

// Round 11
// 591.694 us; speedup vs baseline: 1.2758x; 1.2758x over previous
//
#include <hip/hip_runtime.h>

#define BSZ   4
#define WSEQ  768
#define LSEQ  8192
#define NFFT  8192   // packed complex FFT length (real length 16384)
#define MH    4096
#define EMB   33
#define ORDER 64
#define NT    256    // threads per FFT block (2 blocks/CU at 64KB LDS)

// workspace layout (float units)
#define KFROW   16392          // per-w row: k reals (8192) then 8193 complex in-place
#define WS_TWN  0              // 8192 complex  e^{-2pi t/8192}  (full circle)
#define WS_TW2N 16384          // 8192 complex  e^{-2pi k/16384}
#define WS_H    32768          // h_T: [64][8192] (o-major)
#define WS_KF   557056         // 768 rows x KFROW floats (~50.1 MiB total)

__device__ __forceinline__ int swz(int a){ return a ^ (((a >> 5) & 7) << 2); }

// ---------------- twiddle tables (built in fp64 once per launch) ----------------
__global__ void tables_kernel(float* __restrict__ ws){
  int t = blockIdx.x * 256 + threadIdx.x;      // 0..8191
  const double TWO_PI = 6.283185307179586476925286766559;
  double a1 = -TWO_PI * (double)t / 8192.0;
  double a2 = -TWO_PI * (double)t / 16384.0;
  ws[WS_TWN  + 2*t]   = (float)cos(a1);
  ws[WS_TWN  + 2*t+1] = (float)sin(a1);
  ws[WS_TW2N + 2*t]   = (float)cos(a2);
  ws[WS_TW2N + 2*t+1] = (float)sin(a2);
}

// ---------------- implicit filter MLP: z[8192,33] -> h_T[64][8192] ----------------
__global__ void mlp_kernel(const float* __restrict__ z, const float* __restrict__ freq,
                           const float* __restrict__ w0, const float* __restrict__ b0,
                           const float* __restrict__ w1, const float* __restrict__ b1,
                           const float* __restrict__ w2, const float* __restrict__ b2,
                           float* __restrict__ ws){
  int l = blockIdx.x * 256 + threadIdx.x;
  if (l >= LSEQ) return;
  float zv[EMB];
  #pragma unroll
  for (int e = 0; e < EMB; ++e) zv[e] = z[l*EMB + e];
  float h1[ORDER];
  #pragma unroll 2
  for (int o = 0; o < ORDER; ++o){
    float a = b0[o];
    #pragma unroll
    for (int e = 0; e < EMB; ++e) a += zv[e] * w0[e*ORDER + o];
    h1[o] = sinf(freq[o] * a);
  }
  float h2[ORDER];
  #pragma unroll 2
  for (int o = 0; o < ORDER; ++o){
    float a = b1[o];
    #pragma unroll
    for (int p = 0; p < ORDER; ++p) a += h1[p] * w1[p*ORDER + o];
    h2[o] = sinf(freq[o] * a);
  }
  #pragma unroll 2
  for (int o = 0; o < ORDER; ++o){
    float a = b2[o];
    #pragma unroll
    for (int p = 0; p < ORDER; ++p) a += h2[p] * w2[p*ORDER + o];
    ws[WS_H + o*LSEQ + l] = sinf(freq[o] * a);   // transposed, coalesced per o
  }
}

// ---------------- kgemm: k[w,l] = (h_T[:,l]·wf[:,w]) * exp(-t_l*|delta_w|) ----------------
__global__ void __launch_bounds__(256, 2)
kgemm_kernel(const float* __restrict__ wf, const float* __restrict__ deltas,
             float* __restrict__ ws){
  __shared__ float As[64][128];   // [o][l] 32 KB
  __shared__ float Bs[64][128];   // [o][w] 32 KB
  const int tid = threadIdx.x;
  const int lb = (blockIdx.x & 63) << 7;
  const int wb = (blockIdx.x >> 6) << 7;
  #pragma unroll
  for (int q = 0; q < 8; ++q){
    int idx = q*256 + tid;
    int o = idx >> 5;
    int c = (idx & 31) << 2;
    *(float4*)&As[o][c] = *(const float4*)&ws[WS_H + o*LSEQ + lb + c];
    *(float4*)&Bs[o][c] = *(const float4*)&wf[o*WSEQ + wb + c];
  }
  __syncthreads();
  const int tx = tid & 15;
  const int ty = tid >> 4;
  float acc[8][8];
  #pragma unroll
  for (int i = 0; i < 8; ++i)
    #pragma unroll
    for (int j = 0; j < 8; ++j) acc[i][j] = 0.f;
  #pragma unroll 4
  for (int ko = 0; ko < 64; ++ko){
    float a[8], b[8];
    #pragma unroll
    for (int i = 0; i < 8; ++i) a[i] = As[ko][ty*8 + i];
    #pragma unroll
    for (int j = 0; j < 8; ++j) b[j] = Bs[ko][tx + j*16];
    #pragma unroll
    for (int i = 0; i < 8; ++i)
      #pragma unroll
      for (int j = 0; j < 8; ++j) acc[i][j] += a[i]*b[j];
  }
  const float ool = 1.0f / 8191.0f;
  #pragma unroll
  for (int j = 0; j < 8; ++j){
    int w = wb + tx + j*16;
    float ad = fabsf(deltas[w]);
    float e[8];
    #pragma unroll
    for (int i = 0; i < 8; ++i){
      float tl = (float)(lb + ty*8 + i) * ool;
      e[i] = acc[i][j] * __expf(-tl * ad);
    }
    float* dst = ws + WS_KF + (size_t)w*KFROW + lb + ty*8;
    *(float4*)dst       = make_float4(e[0], e[1], e[2], e[3]);
    *(float4*)(dst + 4) = make_float4(e[4], e[5], e[6], e[7]);
  }
}

// ---------------- radix-16 building blocks ----------------
// multiply by compile-time twiddle: fwd value (cr, ci_fwd); inverse conjugates
template<int SGN>
__device__ __forceinline__ void cmulc(float2& a, float cr, float ci_fwd){
  const float ci = (SGN > 0) ? ci_fwd : -ci_fwd;
  a = make_float2(a.x*cr - a.y*ci, a.x*ci + a.y*cr);
}

// 4-point DFT, in place; out[k] = sum_n in[n] W4^{SGN*n*k}  (W4 = e^{-2pi i/4})
template<int SGN>
__device__ __forceinline__ void dft4(float2& a0, float2& a1, float2& a2, float2& a3){
  float Ar = a0.x + a2.x, Ai = a0.y + a2.y;
  float Br = a0.x - a2.x, Bi = a0.y - a2.y;
  float Cr = a1.x + a3.x, Ci = a1.y + a3.y;
  float Dr = a1.x - a3.x, Di = a1.y - a3.y;
  a0 = make_float2(Ar + Cr, Ai + Ci);
  a2 = make_float2(Ar - Cr, Ai - Ci);
  if (SGN > 0){
    a1 = make_float2(Br + Di, Bi - Dr);   // B - iD
    a3 = make_float2(Br - Di, Bi + Dr);   // B + iD
  } else {
    a1 = make_float2(Br - Di, Bi + Dr);
    a3 = make_float2(Br + Di, Bi - Dr);
  }
}

#define C16A 0.9238795325112867f   // cos(pi/8)
#define C16B 0.3826834323650898f   // sin(pi/8)
#define C16C 0.7071067811865476f   // sqrt(2)/2

// 16-point DFT via 4x4 Cooley-Tukey, constant internal twiddles.
// Input v[n] (n=0..15); output y[k0+4*k1] lands in v[4*k0+k1].
template<int SGN>
__device__ __forceinline__ void dft16(float2 v[16]){
  // level 1: for n1: DFT4 over n2 of v[n1+4*n2] -> t[n1][k0] at v[n1+4*k0]
  dft4<SGN>(v[0], v[4], v[8],  v[12]);
  dft4<SGN>(v[1], v[5], v[9],  v[13]);
  dft4<SGN>(v[2], v[6], v[10], v[14]);
  dft4<SGN>(v[3], v[7], v[11], v[15]);
  // t[n1][k0] *= W16^{n1*k0}   (fwd values; inverse conjugated via SGN)
  cmulc<SGN>(v[5],   C16A, -C16B);   // m=1
  cmulc<SGN>(v[9],   C16C, -C16C);   // m=2
  cmulc<SGN>(v[13],  C16B, -C16A);   // m=3
  cmulc<SGN>(v[6],   C16C, -C16C);   // m=2
  if (SGN > 0) v[10] = make_float2( v[10].y, -v[10].x);   // m=4: *(-i)
  else         v[10] = make_float2(-v[10].y,  v[10].x);   //      *(+i)
  cmulc<SGN>(v[14], -C16C, -C16C);   // m=6
  cmulc<SGN>(v[7],   C16B, -C16A);   // m=3
  cmulc<SGN>(v[11], -C16C, -C16C);   // m=6
  cmulc<SGN>(v[15], -C16A,  C16B);   // m=9
  // level 2: for k0: DFT4 over n1 of v[4*k0+n1] -> y[k0+4*k1] at v[4*k0+k1]
  dft4<SGN>(v[0],  v[1],  v[2],  v[3]);
  dft4<SGN>(v[4],  v[5],  v[6],  v[7]);
  dft4<SGN>(v[8],  v[9],  v[10], v[11]);
  dft4<SGN>(v[12], v[13], v[14], v[15]);
}

// ---------------- Stockham radix-16 pass (in-place, register-staged) ----------------
// reads stride 512 (=N/16); pre-twiddle W8192^{r*u*2^(9-l2)}; write base ((j>>l2)<<(l2+4))+u
template<int SGN>
__device__ __forceinline__ void pass_r16(float2* sC, const float2* __restrict__ twN,
                                         int tid, int l2){
  const int ns = 1 << l2;
  const int sh = 9 - l2;
  float2 ya[16], yb[16];
  int basa, basb;
  {
    const int j = tid;
    const int u = j & (ns - 1);
    const int i1 = u << sh;
    #pragma unroll
    for (int r = 0; r < 16; ++r) ya[r] = sC[swz(j + (r << 9))];
    #pragma unroll
    for (int r = 1; r < 16; ++r){
      float2 t = twN[r * i1];
      float wi = (SGN > 0) ? t.y : -t.y;
      ya[r] = make_float2(ya[r].x*t.x - ya[r].y*wi, ya[r].x*wi + ya[r].y*t.x);
    }
    dft16<SGN>(ya);
    basa = ((j >> l2) << (l2 + 4)) + u;
  }
  {
    const int j = tid + 256;
    const int u = j & (ns - 1);
    const int i1 = u << sh;
    #pragma unroll
    for (int r = 0; r < 16; ++r) yb[r] = sC[swz(j + (r << 9))];
    #pragma unroll
    for (int r = 1; r < 16; ++r){
      float2 t = twN[r * i1];
      float wi = (SGN > 0) ? t.y : -t.y;
      yb[r] = make_float2(yb[r].x*t.x - yb[r].y*wi, yb[r].x*wi + yb[r].y*t.x);
    }
    dft16<SGN>(yb);
    basb = ((j >> l2) << (l2 + 4)) + u;
  }
  __syncthreads();
  #pragma unroll
  for (int k0 = 0; k0 < 4; ++k0){
    #pragma unroll
    for (int k1 = 0; k1 < 4; ++k1){
      const int k = k0 + 4*k1;
      sC[swz(basa + (k << l2))] = ya[4*k0 + k1];
      sC[swz(basb + (k << l2))] = yb[4*k0 + k1];
    }
  }
  __syncthreads();
}

// N=8192 = 2 (fused in pack) * 16^3 : passes at l2 = 1, 5, 9
template<int SGN>
__device__ __forceinline__ void fft_passes(float2* sC,
        const float2* __restrict__ twN, int tid){
  #pragma unroll 1
  for (int p = 0; p < 3; ++p)
    pass_r16<SGN>(sC, twN, tid, 1 + 4*p);
}

// full radix-2 first pass for the inverse (Ns=1, no twiddle)
__device__ __forceinline__ void pass_r2_first(float2* sC, int tid){
  float4 v[16];
  #pragma unroll
  for (int i = 0; i < 16; ++i){
    int j = tid + (i << 8);
    float2 a = sC[swz(j)];
    float2 b = sC[swz(j+4096)];
    v[i] = make_float4(a.x+b.x, a.y+b.y, a.x-b.x, a.y-b.y);
  }
  __syncthreads();
  #pragma unroll
  for (int i = 0; i < 16; ++i){
    int j = tid + (i << 8);
    ((float4*)sC)[swz(2*j) >> 1] = v[i];   // covers swz(2j), swz(2j)+1 == swz(2j+1)
  }
  __syncthreads();
}

// unpack packed-complex FFT C -> real spectrum pair U[t], U[N-t]
__device__ __forceinline__ void unpack_item(int t, const float2* sC,
        const float2* __restrict__ tw2N,
        float& Ukr, float& Uki, float& Unr, float& Uni){
  int tn = (NFFT - t) & (NFFT - 1);
  float2 a = sC[swz(t)];
  float2 b = sC[swz(tn)];
  float Er = 0.5f*(a.x+b.x), Ei = 0.5f*(a.y-b.y);
  float Pr = 0.5f*(a.x-b.x), Pi = 0.5f*(a.y+b.y);
  float Or = Pi, Oi = -Pr;                       // O = -i*P
  float2 tw = tw2N[t];                           // e^{-i pi t / N}
  float Qr = Or*tw.x - Oi*tw.y, Qi = Or*tw.y + Oi*tw.x;
  Ukr = Er + Qr; Uki = Ei + Qi;                  // U[t]   = E + Q
  Unr = Er - Qr; Uni = Qi - Ei;                  // U[N-t] = conj(E - Q)
}

// ---------------- per-w filter spectrum: K = rfft(k,16384)/16384 ----------------
__global__ void __launch_bounds__(NT, 2)
fftk_kernel(float* __restrict__ ws){
  __shared__ float2 sC[NFFT];
  const int tid = threadIdx.x;
  const int w = blockIdx.x;
  float* kfr = ws + WS_KF + (size_t)w * KFROW;
  const float2* twN  = (const float2*)(ws + WS_TWN);
  const float2* tw2N = (const float2*)(ws + WS_TW2N);
  #pragma unroll
  for (int q = 0; q < 16; ++q){                  // pack + trivial first radix-2 (zero pad)
    int j = tid + (q << 8);
    float2 v = ((const float2*)kfr)[j];
    ((float4*)sC)[swz(2*j) >> 1] = make_float4(v.x, v.y, v.x, v.y);
  }
  __syncthreads();
  fft_passes<1>(sC, twN, tid);
  const float sc = 1.0f / 16384.0f;
  #pragma unroll
  for (int i = 0; i < 16; ++i){
    int t = tid + (i << 8);
    float Ukr, Uki, Unr, Uni;
    unpack_item(t, sC, tw2N, Ukr, Uki, Unr, Uni);
    ((float2*)kfr)[t]        = make_float2(Ukr*sc, Uki*sc);
    ((float2*)kfr)[NFFT - t] = make_float2(Unr*sc, Uni*sc);
  }
  if (tid == 0){
    float Ukr, Uki, Unr, Uni;
    unpack_item(MH, sC, tw2N, Ukr, Uki, Unr, Uni);
    ((float2*)kfr)[MH] = make_float2(Ukr*sc, Uki*sc);
  }
}

// fused unpack -> multiply by K -> repack for inverse
__device__ __forceinline__ void pair_item(int t, const float2* sC,
        const float* __restrict__ kfr, const float2* __restrict__ tw2N,
        float& Dtr, float& Dti, float& Dnr, float& Dni){
  float Ukr, Uki, Unr, Uni;
  unpack_item(t, sC, tw2N, Ukr, Uki, Unr, Uni);
  float2 tw = tw2N[t];
  float2 Kk = ((const float2*)kfr)[t];
  float2 Kn = ((const float2*)kfr)[NFFT - t];
  float Ykr = Ukr*Kk.x - Uki*Kk.y, Yki = Ukr*Kk.y + Uki*Kk.x;
  float Ynr = Unr*Kn.x - Uni*Kn.y, Yni = Unr*Kn.y + Uni*Kn.x;
  float Ar = Ykr + Ynr, Ai = Yki - Yni;          // A = Yk + conj(Yn)
  float Br = Ykr - Ynr, Bi = Yki + Yni;          // B = Yk - conj(Yn)
  float Rr = Br*tw.x + Bi*tw.y;                  // R = conj(tw) * B
  float Ri = Bi*tw.x - Br*tw.y;
  Dtr = Ar - Ri; Dti = Ai + Rr;                  // D[t]   = A + iR
  Dnr = Ar + Ri; Dni = Rr - Ai;                  // D[N-t] = conj(A - iR)
}

// ---------------- main: per (b,w) row FFT convolution ----------------
__global__ void __launch_bounds__(NT, 2)
conv_kernel(const float* __restrict__ x, const float* __restrict__ ws,
            const float* __restrict__ Dw, float* __restrict__ out){
  __shared__ float2 sC[NFFT];
  const int tid = threadIdx.x;
  // XCD-aware swizzle: the 4 blocks sharing one K row co-reside on one XCD.
  const int blk = (blockIdx.x & 7) * 384 + (blockIdx.x >> 3);
  const int b = blk & 3, w = blk >> 2;
  const float2* twN  = (const float2*)(ws + WS_TWN);
  const float2* tw2N = (const float2*)(ws + WS_TW2N);
  const float* kfr = ws + WS_KF + (size_t)w * KFROW;
  const size_t rowoff = ((size_t)(b*WSEQ + w)) * LSEQ;
  const float2* xrow = (const float2*)(x + rowoff);
  float2 xr[16];
  #pragma unroll
  for (int q = 0; q < 16; ++q){                  // load row, pack, trivial first pass
    int j = tid + (q << 8);
    float2 v = xrow[j];
    xr[q] = v;
    ((float4*)sC)[swz(2*j) >> 1] = make_float4(v.x, v.y, v.x, v.y);
  }
  __syncthreads();
  fft_passes<1>(sC, twN, tid);                   // forward
  // pair phase (register staged: read all C, then write all D)
  float2 Dt[16], Dn[16];
  float etr = 0.f, eti = 0.f;
  #pragma unroll
  for (int i = 0; i < 16; ++i){
    int t = tid + (i << 8);
    float a, bq, c, d;
    pair_item(t, sC, kfr, tw2N, a, bq, c, d);
    Dt[i] = make_float2(a, bq); Dn[i] = make_float2(c, d);
  }
  if (tid == 0){
    float a, bq, c, d;
    pair_item(MH, sC, kfr, tw2N, a, bq, c, d);
    etr = a; eti = bq;
  }
  __syncthreads();
  #pragma unroll
  for (int i = 0; i < 16; ++i){
    int t = tid + (i << 8);
    int tn = (NFFT - t) & (NFFT - 1);
    sC[swz(t)]  = Dt[i];
    sC[swz(tn)] = Dn[i];
  }
  if (tid == 0){ sC[swz(MH)] = make_float2(etr, eti); }
  __syncthreads();
  // inverse: radix-2 full pass + 3 conjugate radix-16 passes
  pass_r2_first(sC, tid);
  fft_passes<-1>(sC, twN, tid);
  // epilogue: y[2j],y[2j+1] = Re/Im d[j]; add residual x*D[w]
  const float dsc = Dw[w];
  float2* orow = (float2*)(out + rowoff);
  #pragma unroll
  for (int q = 0; q < 16; ++q){
    int j = tid + (q << 8);
    float2 dv = sC[swz(j)];
    float2 o;
    o.x = dv.x + xr[q].x * dsc;
    o.y = dv.y + xr[q].y * dsc;
    orow[j] = o;
  }
}

extern "C" void kernel_launch(void* const* d_in, const int* in_sizes, int n_in,
                              void* d_out, int out_size, void* d_ws, size_t ws_size,
                              hipStream_t stream){
  const float* x      = (const float*)d_in[0];
  const float* z      = (const float*)d_in[1];
  const float* freq   = (const float*)d_in[2];
  const float* w0     = (const float*)d_in[3];
  const float* b0     = (const float*)d_in[4];
  const float* w1     = (const float*)d_in[5];
  const float* b1     = (const float*)d_in[6];
  const float* w2     = (const float*)d_in[7];
  const float* b2     = (const float*)d_in[8];
  const float* wf     = (const float*)d_in[9];
  const float* deltas = (const float*)d_in[10];
  const float* Dw     = (const float*)d_in[11];
  float* ws  = (float*)d_ws;
  float* out = (float*)d_out;

  tables_kernel<<<dim3(32),  dim3(256), 0, stream>>>(ws);
  mlp_kernel   <<<dim3(32),  dim3(256), 0, stream>>>(z, freq, w0, b0, w1, b1, w2, b2, ws);
  kgemm_kernel <<<dim3(384), dim3(256), 0, stream>>>(wf, deltas, ws);
  fftk_kernel  <<<dim3(WSEQ), dim3(NT), 0, stream>>>(ws);
  conv_kernel  <<<dim3(BSZ*WSEQ), dim3(NT), 0, stream>>>(x, ws, Dw, out);
}